// Round 6
// baseline (511.254 us; speedup 1.0000x reference)
//
#include <hip/hip_runtime.h>

// ---------------------------------------------------------------------------
// VectorQuantizer: z(16,32,32,256) fp32, embedding(256,8192), cluster_size(8192),
// embedding_avg(256,8192).
// Outputs (concat, fp32): quantize_st[4194304], diff[1], embed_ind[16384](as float),
// new_embedding[2097152], new_cluster_size[8192], new_embedding_avg[2097152]
//
// R6: embed_sum scattered in [d][e] layout at OUT_NEWAVG -> finalize becomes
//     elementwise-in-place (no transpose pass, no fin2b). 4 kernels.
//     prep and argmin are R5-verbatim (proven).
// Aliasing timeline:
//   OUT_Q:      z_hi/z_lo planes (prep) -> quantize_st (gather)
//   OUT_NEWAVG: embsum_de [d][e] zeroed (prep), scattered (gather),
//               read+overwritten elementwise by fin -> new_embedding_avg
//   OUT_NEWEMB: new_embedding (fin)
// ---------------------------------------------------------------------------

#define DIMC  256
#define NEMB  8192
#define NROWS 16384

// d_out offsets (float elements)
#define OUT_Q      0u
#define OUT_DIFF   4194304u
#define OUT_IDX    4194305u
#define OUT_NEWEMB 4210689u
#define OUT_NEWCS  6307841u
#define OUT_NEWAVG 6316033u

// d_ws offsets (float elements) — total 2146308 floats = 8.59 MB
#define WS_EHI    0u          // bf16[8192][256] transposed emb hi
#define WS_ELO    1048576u    // bf16[8192][256] transposed emb lo
#define WS_COUNT  2097152u    // [NEMB]
#define WS_DIFF   2105344u    // [1]
#define WS_N      2105345u    // [1]  (written by prep, closed-form)
#define WS_ENORM  2105346u    // [NEMB] exact ||e||^2
#define WS_PACK   2113540u    // u64[NROWS]; byte 8454160 % 16 == 0 (16-aligned)

typedef __attribute__((ext_vector_type(8))) short short8;
typedef __attribute__((ext_vector_type(4))) float f32x4;

// round-to-nearest-even fp32 -> bf16 split: x ~= hi + lo
__device__ inline void split_bf16(float x, unsigned short& h, unsigned short& l) {
  unsigned u = __float_as_uint(x);
  unsigned r = u + 0x7FFFu + ((u >> 16) & 1u);
  h = (unsigned short)(r >> 16);
  float hf = __uint_as_float((unsigned)h << 16);
  float lo = x - hf;
  unsigned u2 = __float_as_uint(lo);
  unsigned r2 = u2 + 0x7FFFu + ((u2 >> 16) & 1u);
  l = (unsigned short)(r2 >> 16);
}

__device__ inline float bf16_f(unsigned short u) {
  return __uint_as_float((unsigned)u << 16);
}

// ---------------------------------------------------------------------------
// Fused prep (R5 verbatim): [0,1024) z split | [1024,1536) emb transpose/split
// | [1536,2048) embsum zero | [2048,2176) exact enorm | [2176,2184) pack 0xFF
// | [2184] count+diff zero | [2185] sum(cs) -> n closed-form
__global__ __launch_bounds__(256) void prep_kernel(
    const float* __restrict__ z, const float* __restrict__ emb,
    const float* __restrict__ cs, unsigned short* __restrict__ z_hi,
    unsigned short* __restrict__ z_lo, unsigned short* __restrict__ e_hi,
    unsigned short* __restrict__ e_lo, float* __restrict__ enorm,
    float* __restrict__ embsum, unsigned long long* __restrict__ pack,
    float* __restrict__ count_diff, float* __restrict__ n_out) {
  const int b = blockIdx.x;
  const int t = threadIdx.x;
  __shared__ float tile[64][68];
  __shared__ float red[4][64];

  if (b < 1024) {
#pragma unroll
    for (int it = 0; it < 4; ++it) {
      const int idx = (b * 256 + t) + it * 262144;
      const float4 v = reinterpret_cast<const float4*>(z)[idx];
      ushort4 h, l;
      split_bf16(v.x, h.x, l.x);
      split_bf16(v.y, h.y, l.y);
      split_bf16(v.z, h.z, l.z);
      split_bf16(v.w, h.w, l.w);
      reinterpret_cast<ushort4*>(z_hi)[idx] = h;
      reinterpret_cast<ushort4*>(z_lo)[idx] = l;
    }
  } else if (b < 1536) {
    const int bb = b - 1024;
    const int n0 = (bb & 127) * 64;
    const int k0 = (bb >> 7) * 64;
    const int c4 = (t & 15) * 4;
    const int rr = t >> 4;
#pragma unroll
    for (int i = 0; i < 4; ++i) {
      const int kl = rr + i * 16;
      const float4 v = *reinterpret_cast<const float4*>(
          &emb[(size_t)(k0 + kl) * NEMB + n0 + c4]);
      *reinterpret_cast<float4*>(&tile[kl][c4]) = v;
    }
    __syncthreads();
#pragma unroll
    for (int i = 0; i < 4; ++i) {
      const int nr = rr + i * 16;
      float4 v;
      v.x = tile[c4 + 0][nr];
      v.y = tile[c4 + 1][nr];
      v.z = tile[c4 + 2][nr];
      v.w = tile[c4 + 3][nr];
      const size_t off = (size_t)(n0 + nr) * DIMC + k0 + c4;
      ushort4 h, l;
      split_bf16(v.x, h.x, l.x);
      split_bf16(v.y, h.y, l.y);
      split_bf16(v.z, h.z, l.z);
      split_bf16(v.w, h.w, l.w);
      *reinterpret_cast<ushort4*>(&e_hi[off]) = h;
      *reinterpret_cast<ushort4*>(&e_lo[off]) = l;
    }
  } else if (b < 2048) {
    const int bb = b - 1536;
    const float4 zero = {0.f, 0.f, 0.f, 0.f};
#pragma unroll
    for (int it = 0; it < 4; ++it)
      reinterpret_cast<float4*>(embsum)[bb * 1024 + t + it * 256] = zero;
  } else if (b < 2176) {
    // exact enorm, R2 summation order
    const int l = t & 63;
    const int dg = t >> 6;
    const int e = (b - 2048) * 64 + l;
    float s = 0.f;
#pragma unroll 8
    for (int d = dg * 64; d < dg * 64 + 64; ++d) {
      const float v = emb[(size_t)d * NEMB + e];
      s = fmaf(v, v, s);
    }
    red[dg][l] = s;
    __syncthreads();
    if (dg == 0) enorm[e] = red[0][l] + red[1][l] + red[2][l] + red[3][l];
  } else if (b < 2184) {
    const int bb = b - 2176;
    const uint4 ff = {~0u, ~0u, ~0u, ~0u};  // ws_pack is 16-aligned
#pragma unroll
    for (int it = 0; it < 4; ++it)
      reinterpret_cast<uint4*>(pack)[bb * 1024 + t + it * 256] = ff;
  } else if (b == 2184) {
    for (int i = t; i < 8193; i += 256) count_diff[i] = 0.f;  // count + diff
  } else {
    // n = 0.99*sum(cs) + 0.01*16384 (sum(count) == NROWS exactly)
    float s = 0.f;
#pragma unroll
    for (int i = 0; i < 32; ++i) s += cs[t + i * 256];
#pragma unroll
    for (int off = 32; off > 0; off >>= 1) s += __shfl_down(s, off, 64);
    if ((t & 63) == 0) red[0][t >> 6] = s;
    __syncthreads();
    if (t == 0)
      n_out[0] = 0.99f * (red[0][0] + red[0][1] + red[0][2] + red[0][3]) +
                 163.84f;
  }
}

// ---------------------------------------------------------------------------
// MFMA dist+argmin — R4/R5 kernel, VERBATIM (proven).
__global__ __launch_bounds__(256, 2) void argmin_mfma_kernel(
    const unsigned short* __restrict__ z_hi, const unsigned short* __restrict__ z_lo,
    const unsigned short* __restrict__ e_hi, const unsigned short* __restrict__ e_lo,
    const float* __restrict__ enorm, unsigned long long* __restrict__ pack) {
  __shared__ short za[16384];  // 32 KB
  __shared__ short eb[16384];  // 32 KB
  const int tid = threadIdx.x;
  const int bid = blockIdx.x;
  const int r0 = (bid >> 2) * 128;
  const int ebase = (bid & 3) * 2048;
  const int tx = tid & 15;
  const int q = (tid >> 4) & 3;
  const int wave = tid >> 6;
  const int wm = wave & 1;   // row half
  const int wn = wave >> 1;  // col half

  float rmin[4][4];
  int ridx[4][4];
#pragma unroll
  for (int i = 0; i < 4; ++i)
#pragma unroll
    for (int r = 0; r < 4; ++r) { rmin[i][r] = 3.4028235e38f; ridx[i][r] = 0; }

  for (int nt = 0; nt < 16; ++nt) {
    const int n0 = ebase + nt * 128;
    f32x4 acc[4][4];
#pragma unroll
    for (int i = 0; i < 4; ++i)
#pragma unroll
      for (int j = 0; j < 4; ++j) acc[i][j] = (f32x4)0.0f;

    for (int kt = 0; kt < 4; ++kt) {
      const int k0 = kt * 64;
      __syncthreads();  // previous tile fully consumed
#pragma unroll
      for (int it = 0; it < 8; ++it) {
        const int P = tid + it * 256;  // chunk id 0..2047
        const int row = P >> 4;
        const int p = P & 15;
        const int o = (p & 7) ^ (row & 7);
        const unsigned short* zsrc =
            ((p & 8) ? z_lo : z_hi) + (size_t)(r0 + row) * DIMC + k0 + o * 8;
        __builtin_amdgcn_global_load_lds(
            (const __attribute__((address_space(1))) unsigned int*)zsrc,
            (__attribute__((address_space(3))) unsigned int*)&za[P * 8], 16, 0, 0);
        const unsigned short* esrc =
            ((p & 8) ? e_lo : e_hi) + (size_t)(n0 + row) * DIMC + k0 + o * 8;
        __builtin_amdgcn_global_load_lds(
            (const __attribute__((address_space(1))) unsigned int*)esrc,
            (__attribute__((address_space(3))) unsigned int*)&eb[P * 8], 16, 0, 0);
      }
      __syncthreads();  // drain + publish
#pragma unroll
      for (int ks = 0; ks < 2; ++ks) {
        short8 ah[4], al[4], bh[4], bl[4];
#pragma unroll
        for (int i = 0; i < 4; ++i) {
          const int rl = wm * 64 + i * 16 + tx;
          const int oa = (ks * 4 + q) ^ (rl & 7);
          ah[i] = *reinterpret_cast<const short8*>(&za[rl * 128 + oa * 8]);
          al[i] = *reinterpret_cast<const short8*>(&za[rl * 128 + (oa + 8) * 8]);
          const int cl = wn * 64 + i * 16 + tx;
          const int ob = (ks * 4 + q) ^ (cl & 7);
          bh[i] = *reinterpret_cast<const short8*>(&eb[cl * 128 + ob * 8]);
          bl[i] = *reinterpret_cast<const short8*>(&eb[cl * 128 + (ob + 8) * 8]);
        }
#pragma unroll
        for (int i = 0; i < 4; ++i)
#pragma unroll
          for (int j = 0; j < 4; ++j) {
            acc[i][j] = __builtin_amdgcn_mfma_f32_16x16x32_bf16(ah[i], bh[j],
                                                               acc[i][j], 0, 0, 0);
            acc[i][j] = __builtin_amdgcn_mfma_f32_16x16x32_bf16(ah[i], bl[j],
                                                               acc[i][j], 0, 0, 0);
            acc[i][j] = __builtin_amdgcn_mfma_f32_16x16x32_bf16(al[i], bh[j],
                                                               acc[i][j], 0, 0, 0);
          }
      }
    }
    // epilogue: score = ||e||^2 - 2*dot, running first-min argmin.
#pragma unroll
    for (int j = 0; j < 4; ++j) {
      const int col = n0 + wn * 64 + j * 16 + tx;
      const float en = enorm[col];
#pragma unroll
      for (int i = 0; i < 4; ++i)
#pragma unroll
        for (int r = 0; r < 4; ++r) {
          const float s = en - 2.0f * acc[i][j][r];
          if (s < rmin[i][r]) { rmin[i][r] = s; ridx[i][r] = col; }
        }
    }
  }
#pragma unroll
  for (int i = 0; i < 4; ++i)
#pragma unroll
    for (int r = 0; r < 4; ++r) {
      float v = rmin[i][r];
      int ix = ridx[i][r];
#pragma unroll
      for (int off = 1; off < 16; off <<= 1) {
        const float ov = __shfl_xor(v, off, 16);
        const int oi = __shfl_xor(ix, off, 16);
        if (ov < v || (ov == v && oi < ix)) { v = ov; ix = oi; }
      }
      if (tx == 0) {
        const unsigned int fb = __float_as_uint(v);
        const unsigned int sb = (fb & 0x80000000u) ? ~fb : (fb | 0x80000000u);
        const unsigned long long key =
            ((unsigned long long)sb << 13) | (unsigned long long)(unsigned)ix;
        atomicMin(&pack[r0 + wm * 64 + i * 16 + q * 4 + r], key);
      }
    }
}

// ---------------------------------------------------------------------------
// Gather quantize (reconstruct fp32 = hi+lo), extract index, diff partial,
// scatter embed_sum in [d][e] layout + count. 1 wave per row.
__global__ __launch_bounds__(256) void gather_update_kernel(
    const float* __restrict__ z, const unsigned short* __restrict__ e_hi,
    const unsigned short* __restrict__ e_lo,
    const unsigned long long* __restrict__ pack, float* __restrict__ out_q,
    float* __restrict__ out_idx, float* __restrict__ embsum_de,
    float* __restrict__ count, float* __restrict__ diff_acc) {
  const int row = blockIdx.x * 4 + (threadIdx.x >> 6);
  const int lane = threadIdx.x & 63;
  const int e = (int)(pack[row] & 8191ULL);
  if (lane == 0) out_idx[row] = (float)e;
  const float4 zv =
      *reinterpret_cast<const float4*>(&z[(size_t)row * DIMC + lane * 4]);
  const ushort4 h =
      *reinterpret_cast<const ushort4*>(&e_hi[(size_t)e * DIMC + lane * 4]);
  const ushort4 l =
      *reinterpret_cast<const ushort4*>(&e_lo[(size_t)e * DIMC + lane * 4]);
  const float q0 = bf16_f(h.x) + bf16_f(l.x);
  const float q1 = bf16_f(h.y) + bf16_f(l.y);
  const float q2 = bf16_f(h.z) + bf16_f(l.z);
  const float q3 = bf16_f(h.w) + bf16_f(l.w);
  const float d0 = q0 - zv.x, d1 = q1 - zv.y, d2 = q2 - zv.z, d3 = q3 - zv.w;
  float4 st;
  st.x = zv.x + d0; st.y = zv.y + d1; st.z = zv.z + d2; st.w = zv.w + d3;
  *reinterpret_cast<float4*>(&out_q[(size_t)row * DIMC + lane * 4]) = st;

  // [d][e] scatter: same atomic count, enables elementwise in-place finalize
  atomicAdd(&embsum_de[(size_t)(lane * 4 + 0) * NEMB + e], zv.x);
  atomicAdd(&embsum_de[(size_t)(lane * 4 + 1) * NEMB + e], zv.y);
  atomicAdd(&embsum_de[(size_t)(lane * 4 + 2) * NEMB + e], zv.z);
  atomicAdd(&embsum_de[(size_t)(lane * 4 + 3) * NEMB + e], zv.w);

  float local = d0 * d0 + d1 * d1 + d2 * d2 + d3 * d3;
#pragma unroll
  for (int off = 32; off > 0; off >>= 1) local += __shfl_down(local, off, 64);

  __shared__ float dred[4];
  if (lane == 0) {
    dred[threadIdx.x >> 6] = local;
    atomicAdd(&count[e], 1.0f);
  }
  __syncthreads();
  if (threadIdx.x == 0)
    atomicAdd(diff_acc, dred[0] + dred[1] + dred[2] + dred[3]);
}

// ---------------------------------------------------------------------------
// fin: blocks [0,2048): elementwise g (float4): avg = 0.99*eavg + 0.01*embsum_de
// (read g -> overwrite g in place, race-free), out_emb = avg / smoothed(e).
// blocks [2048,2080): new_cluster_size; diff finalize at g==0.
__global__ __launch_bounds__(256) void fin_kernel(
    const float* __restrict__ eavg, const float* __restrict__ cs,
    const float* __restrict__ count, const float* __restrict__ n_ptr,
    const float* __restrict__ diff_acc, float* __restrict__ avg_io,
    float* __restrict__ out_emb, float* __restrict__ out_ncs,
    float* __restrict__ out_diff) {
  const int b = blockIdx.x;
  const int t = threadIdx.x;
  if (b < 2048) {
    const int g4 = b * 256 + t;        // float4 index
    const int g = g4 * 4;
    const int e = g & 8191;            // e, e+1, e+2, e+3 (aligned, same d)
    const float n = n_ptr[0];
    const float4 sv = reinterpret_cast<const float4*>(avg_io)[g4];
    const float4 av = reinterpret_cast<const float4*>(eavg)[g4];
    float4 avg;
    avg.x = av.x * 0.99f + 0.01f * sv.x;
    avg.y = av.y * 0.99f + 0.01f * sv.y;
    avg.z = av.z * 0.99f + 0.01f * sv.z;
    avg.w = av.w * 0.99f + 0.01f * sv.w;
    reinterpret_cast<float4*>(avg_io)[g4] = avg;
    const float inv_den = 1.0f / (n + 0.08192f);
    float4 o;
    o.x = avg.x / ((cs[e + 0] * 0.99f + 0.01f * count[e + 0] + 1e-5f) * inv_den * n);
    o.y = avg.y / ((cs[e + 1] * 0.99f + 0.01f * count[e + 1] + 1e-5f) * inv_den * n);
    o.z = avg.z / ((cs[e + 2] * 0.99f + 0.01f * count[e + 2] + 1e-5f) * inv_den * n);
    o.w = avg.w / ((cs[e + 3] * 0.99f + 0.01f * count[e + 3] + 1e-5f) * inv_den * n);
    reinterpret_cast<float4*>(out_emb)[g4] = o;
  } else {
    const int g = (b - 2048) * 256 + t;
    out_ncs[g] = cs[g] * 0.99f + 0.01f * count[g];
    if (g == 0) out_diff[0] = diff_acc[0] * (1.0f / 4194304.0f);
  }
}

// ---------------------------------------------------------------------------
extern "C" void kernel_launch(void* const* d_in, const int* in_sizes, int n_in,
                              void* d_out, int out_size, void* d_ws,
                              size_t ws_size, hipStream_t stream) {
  const float* z = (const float*)d_in[0];
  const float* emb = (const float*)d_in[1];
  const float* cs = (const float*)d_in[2];
  const float* eavg = (const float*)d_in[3];
  float* out = (float*)d_out;
  float* ws = (float*)d_ws;

  unsigned short* e_hi = (unsigned short*)(ws + WS_EHI);
  unsigned short* e_lo = (unsigned short*)(ws + WS_ELO);
  float* ws_count = ws + WS_COUNT;
  float* ws_diff = ws + WS_DIFF;
  float* ws_n = ws + WS_N;
  float* ws_enorm = ws + WS_ENORM;
  unsigned long long* ws_pack = (unsigned long long*)(ws + WS_PACK);

  // d_out-aliased scratch (rewritten before readback):
  unsigned short* z_hi = (unsigned short*)(out + OUT_Q);
  unsigned short* z_lo = (unsigned short*)(out + OUT_Q + 2097152);
  float* embsum_de = out + OUT_NEWAVG;  // [d][e], becomes new_embedding_avg

  prep_kernel<<<2186, 256, 0, stream>>>(z, emb, cs, z_hi, z_lo, e_hi, e_lo,
                                        ws_enorm, embsum_de, ws_pack, ws_count,
                                        ws_n);
  argmin_mfma_kernel<<<512, 256, 0, stream>>>(z_hi, z_lo, e_hi, e_lo, ws_enorm,
                                              ws_pack);
  gather_update_kernel<<<NROWS / 4, 256, 0, stream>>>(
      z, e_hi, e_lo, ws_pack, out + OUT_Q, out + OUT_IDX, embsum_de, ws_count,
      ws_diff);
  fin_kernel<<<2080, 256, 0, stream>>>(eavg, cs, ws_count, ws_n, ws_diff,
                                       embsum_de, out + OUT_NEWEMB,
                                       out + OUT_NEWCS, out + OUT_DIFF);
}

// Round 7
// 409.452 us; speedup vs baseline: 1.2486x; 1.2486x over previous
//
#include <hip/hip_runtime.h>

// ---------------------------------------------------------------------------
// VectorQuantizer: z(16,32,32,256) fp32, embedding(256,8192), cluster_size(8192),
// embedding_avg(256,8192).
// Outputs (concat, fp32): quantize_st[4194304], diff[1], embed_ind[16384](as float),
// new_embedding[2097152], new_cluster_size[8192], new_embedding_avg[2097152]
//
// R7: R5 package (proven 390 us) + argmin widened to 512-thread / 128x256
//     e-tile (pure scheduling change: same per-accumulator arithmetic order,
//     same LDS chunk layout, 25% less staging, 2x MFMA per barrier).
//     gather reverted to [e][d] coalesced scatter (R6's [d][e] was 228 us).
// Aliasing timeline:
//   OUT_Q:      z_hi/z_lo planes (prep) -> quantize_st (gather)
//   OUT_NEWAVG: embsum [e][d] zeroed (prep), scattered (gather), read (fin1),
//               -> new_embedding_avg (fin2b)
//   OUT_NEWEMB: new_embedding (fin1), read by fin2b
// ---------------------------------------------------------------------------

#define DIMC  256
#define NEMB  8192
#define NROWS 16384

// d_out offsets (float elements)
#define OUT_Q      0u
#define OUT_DIFF   4194304u
#define OUT_IDX    4194305u
#define OUT_NEWEMB 4210689u
#define OUT_NEWCS  6307841u
#define OUT_NEWAVG 6316033u

// d_ws offsets (float elements) — total 2146308 floats = 8.59 MB
#define WS_EHI    0u          // bf16[8192][256] transposed emb hi
#define WS_ELO    1048576u    // bf16[8192][256] transposed emb lo
#define WS_COUNT  2097152u    // [NEMB]
#define WS_DIFF   2105344u    // [1]
#define WS_N      2105345u    // [1]  (written by prep, closed-form)
#define WS_ENORM  2105346u    // [NEMB] exact ||e||^2
#define WS_PACK   2113540u    // u64[NROWS]; byte 8454160 % 16 == 0 (16-aligned)

typedef __attribute__((ext_vector_type(8))) short short8;
typedef __attribute__((ext_vector_type(4))) float f32x4;

// round-to-nearest-even fp32 -> bf16 split: x ~= hi + lo
__device__ inline void split_bf16(float x, unsigned short& h, unsigned short& l) {
  unsigned u = __float_as_uint(x);
  unsigned r = u + 0x7FFFu + ((u >> 16) & 1u);
  h = (unsigned short)(r >> 16);
  float hf = __uint_as_float((unsigned)h << 16);
  float lo = x - hf;
  unsigned u2 = __float_as_uint(lo);
  unsigned r2 = u2 + 0x7FFFu + ((u2 >> 16) & 1u);
  l = (unsigned short)(r2 >> 16);
}

__device__ inline float bf16_f(unsigned short u) {
  return __uint_as_float((unsigned)u << 16);
}

// ---------------------------------------------------------------------------
// Fused prep (R5 verbatim): [0,1024) z split | [1024,1536) emb transpose/split
// | [1536,2048) embsum zero | [2048,2176) exact enorm | [2176,2184) pack 0xFF
// | [2184] count+diff zero | [2185] sum(cs) -> n closed-form
__global__ __launch_bounds__(256) void prep_kernel(
    const float* __restrict__ z, const float* __restrict__ emb,
    const float* __restrict__ cs, unsigned short* __restrict__ z_hi,
    unsigned short* __restrict__ z_lo, unsigned short* __restrict__ e_hi,
    unsigned short* __restrict__ e_lo, float* __restrict__ enorm,
    float* __restrict__ embsum, unsigned long long* __restrict__ pack,
    float* __restrict__ count_diff, float* __restrict__ n_out) {
  const int b = blockIdx.x;
  const int t = threadIdx.x;
  __shared__ float tile[64][68];
  __shared__ float red[4][64];

  if (b < 1024) {
#pragma unroll
    for (int it = 0; it < 4; ++it) {
      const int idx = (b * 256 + t) + it * 262144;
      const float4 v = reinterpret_cast<const float4*>(z)[idx];
      ushort4 h, l;
      split_bf16(v.x, h.x, l.x);
      split_bf16(v.y, h.y, l.y);
      split_bf16(v.z, h.z, l.z);
      split_bf16(v.w, h.w, l.w);
      reinterpret_cast<ushort4*>(z_hi)[idx] = h;
      reinterpret_cast<ushort4*>(z_lo)[idx] = l;
    }
  } else if (b < 1536) {
    const int bb = b - 1024;
    const int n0 = (bb & 127) * 64;
    const int k0 = (bb >> 7) * 64;
    const int c4 = (t & 15) * 4;
    const int rr = t >> 4;
#pragma unroll
    for (int i = 0; i < 4; ++i) {
      const int kl = rr + i * 16;
      const float4 v = *reinterpret_cast<const float4*>(
          &emb[(size_t)(k0 + kl) * NEMB + n0 + c4]);
      *reinterpret_cast<float4*>(&tile[kl][c4]) = v;
    }
    __syncthreads();
#pragma unroll
    for (int i = 0; i < 4; ++i) {
      const int nr = rr + i * 16;
      float4 v;
      v.x = tile[c4 + 0][nr];
      v.y = tile[c4 + 1][nr];
      v.z = tile[c4 + 2][nr];
      v.w = tile[c4 + 3][nr];
      const size_t off = (size_t)(n0 + nr) * DIMC + k0 + c4;
      ushort4 h, l;
      split_bf16(v.x, h.x, l.x);
      split_bf16(v.y, h.y, l.y);
      split_bf16(v.z, h.z, l.z);
      split_bf16(v.w, h.w, l.w);
      *reinterpret_cast<ushort4*>(&e_hi[off]) = h;
      *reinterpret_cast<ushort4*>(&e_lo[off]) = l;
    }
  } else if (b < 2048) {
    const int bb = b - 1536;
    const float4 zero = {0.f, 0.f, 0.f, 0.f};
#pragma unroll
    for (int it = 0; it < 4; ++it)
      reinterpret_cast<float4*>(embsum)[bb * 1024 + t + it * 256] = zero;
  } else if (b < 2176) {
    // exact enorm, R2 summation order
    const int l = t & 63;
    const int dg = t >> 6;
    const int e = (b - 2048) * 64 + l;
    float s = 0.f;
#pragma unroll 8
    for (int d = dg * 64; d < dg * 64 + 64; ++d) {
      const float v = emb[(size_t)d * NEMB + e];
      s = fmaf(v, v, s);
    }
    red[dg][l] = s;
    __syncthreads();
    if (dg == 0) enorm[e] = red[0][l] + red[1][l] + red[2][l] + red[3][l];
  } else if (b < 2184) {
    const int bb = b - 2176;
    const uint4 ff = {~0u, ~0u, ~0u, ~0u};  // ws_pack is 16-aligned
#pragma unroll
    for (int it = 0; it < 4; ++it)
      reinterpret_cast<uint4*>(pack)[bb * 1024 + t + it * 256] = ff;
  } else if (b == 2184) {
    for (int i = t; i < 8193; i += 256) count_diff[i] = 0.f;  // count + diff
  } else {
    // n = 0.99*sum(cs) + 0.01*16384 (sum(count) == NROWS exactly)
    float s = 0.f;
#pragma unroll
    for (int i = 0; i < 32; ++i) s += cs[t + i * 256];
#pragma unroll
    for (int off = 32; off > 0; off >>= 1) s += __shfl_down(s, off, 64);
    if ((t & 63) == 0) red[0][t >> 6] = s;
    __syncthreads();
    if (t == 0)
      n_out[0] = 0.99f * (red[0][0] + red[0][1] + red[0][2] + red[0][3]) +
                 163.84f;
  }
}

// ---------------------------------------------------------------------------
// MFMA dist+argmin. 512 threads = 8 waves (wm = wave&1 row-half, wn = wave>>1
// in 0..3 col-quarter), tile 128 rows x 256 codes per nt, wave tile 64x64
// (4x4 of 16x16x32 mfma), BK=64, 3 mfma per (frag,kstep) — identical
// per-accumulator arithmetic order to the proven R5 kernel (kt asc, ks asc,
// hh/hl/lh). Grid 512: bid>>2 = row-tile, bid&3 = 2048-code chunk, nt = 8.
// LDS: za 32KB (128 rows), eb 64KB (256 codes); chunk p of row n holds
// k-octet ((p&7)^(n&7)) of plane (p>>3). Staging via global_load_lds w=16.
__global__ __launch_bounds__(512, 2) void argmin_mfma_kernel(
    const unsigned short* __restrict__ z_hi, const unsigned short* __restrict__ z_lo,
    const unsigned short* __restrict__ e_hi, const unsigned short* __restrict__ e_lo,
    const float* __restrict__ enorm, unsigned long long* __restrict__ pack) {
  __shared__ short za[16384];  // 32 KB: 128 rows x 128 shorts
  __shared__ short eb[32768];  // 64 KB: 256 codes x 128 shorts
  const int tid = threadIdx.x;
  const int bid = blockIdx.x;
  const int r0 = (bid >> 2) * 128;
  const int ebase = (bid & 3) * 2048;
  const int tx = tid & 15;
  const int q = (tid >> 4) & 3;
  const int wave = tid >> 6;
  const int wm = wave & 1;   // row half
  const int wn = wave >> 1;  // col quarter (0..3)

  float rmin[4][4];
  int ridx[4][4];
#pragma unroll
  for (int i = 0; i < 4; ++i)
#pragma unroll
    for (int r = 0; r < 4; ++r) { rmin[i][r] = 3.4028235e38f; ridx[i][r] = 0; }

  for (int nt = 0; nt < 8; ++nt) {
    const int n0 = ebase + nt * 256;
    f32x4 acc[4][4];
#pragma unroll
    for (int i = 0; i < 4; ++i)
#pragma unroll
      for (int j = 0; j < 4; ++j) acc[i][j] = (f32x4)0.0f;

    for (int kt = 0; kt < 4; ++kt) {
      const int k0 = kt * 64;
      __syncthreads();  // previous tile fully consumed
#pragma unroll
      for (int it = 0; it < 4; ++it) {  // z: 2048 chunks / 512 thr
        const int P = tid + it * 512;
        const int row = P >> 4;
        const int p = P & 15;
        const int o = (p & 7) ^ (row & 7);
        const unsigned short* zsrc =
            ((p & 8) ? z_lo : z_hi) + (size_t)(r0 + row) * DIMC + k0 + o * 8;
        __builtin_amdgcn_global_load_lds(
            (const __attribute__((address_space(1))) unsigned int*)zsrc,
            (__attribute__((address_space(3))) unsigned int*)&za[P * 8], 16, 0, 0);
      }
#pragma unroll
      for (int it = 0; it < 8; ++it) {  // e: 4096 chunks / 512 thr
        const int P = tid + it * 512;
        const int row = P >> 4;  // 0..255
        const int p = P & 15;
        const int o = (p & 7) ^ (row & 7);
        const unsigned short* esrc =
            ((p & 8) ? e_lo : e_hi) + (size_t)(n0 + row) * DIMC + k0 + o * 8;
        __builtin_amdgcn_global_load_lds(
            (const __attribute__((address_space(1))) unsigned int*)esrc,
            (__attribute__((address_space(3))) unsigned int*)&eb[P * 8], 16, 0, 0);
      }
      __syncthreads();  // drain + publish
#pragma unroll
      for (int ks = 0; ks < 2; ++ks) {
        short8 ah[4], al[4], bh[4], bl[4];
#pragma unroll
        for (int i = 0; i < 4; ++i) {
          const int rl = wm * 64 + i * 16 + tx;
          const int oa = (ks * 4 + q) ^ (rl & 7);
          ah[i] = *reinterpret_cast<const short8*>(&za[rl * 128 + oa * 8]);
          al[i] = *reinterpret_cast<const short8*>(&za[rl * 128 + (oa + 8) * 8]);
          const int cl = wn * 64 + i * 16 + tx;
          const int ob = (ks * 4 + q) ^ (cl & 7);
          bh[i] = *reinterpret_cast<const short8*>(&eb[cl * 128 + ob * 8]);
          bl[i] = *reinterpret_cast<const short8*>(&eb[cl * 128 + (ob + 8) * 8]);
        }
#pragma unroll
        for (int i = 0; i < 4; ++i)
#pragma unroll
          for (int j = 0; j < 4; ++j) {
            acc[i][j] = __builtin_amdgcn_mfma_f32_16x16x32_bf16(ah[i], bh[j],
                                                               acc[i][j], 0, 0, 0);
            acc[i][j] = __builtin_amdgcn_mfma_f32_16x16x32_bf16(ah[i], bl[j],
                                                               acc[i][j], 0, 0, 0);
            acc[i][j] = __builtin_amdgcn_mfma_f32_16x16x32_bf16(al[i], bh[j],
                                                               acc[i][j], 0, 0, 0);
          }
      }
    }
    // epilogue: score = ||e||^2 - 2*dot, running first-min argmin.
#pragma unroll
    for (int j = 0; j < 4; ++j) {
      const int col = n0 + wn * 64 + j * 16 + tx;
      const float en = enorm[col];
#pragma unroll
      for (int i = 0; i < 4; ++i)
#pragma unroll
        for (int r = 0; r < 4; ++r) {
          const float s = en - 2.0f * acc[i][j][r];
          if (s < rmin[i][r]) { rmin[i][r] = s; ridx[i][r] = col; }
        }
    }
  }
#pragma unroll
  for (int i = 0; i < 4; ++i)
#pragma unroll
    for (int r = 0; r < 4; ++r) {
      float v = rmin[i][r];
      int ix = ridx[i][r];
#pragma unroll
      for (int off = 1; off < 16; off <<= 1) {
        const float ov = __shfl_xor(v, off, 16);
        const int oi = __shfl_xor(ix, off, 16);
        if (ov < v || (ov == v && oi < ix)) { v = ov; ix = oi; }
      }
      if (tx == 0) {
        const unsigned int fb = __float_as_uint(v);
        const unsigned int sb = (fb & 0x80000000u) ? ~fb : (fb | 0x80000000u);
        const unsigned long long key =
            ((unsigned long long)sb << 13) | (unsigned long long)(unsigned)ix;
        atomicMin(&pack[r0 + wm * 64 + i * 16 + q * 4 + r], key);
      }
    }
}

// ---------------------------------------------------------------------------
// Gather quantize (reconstruct fp32 = hi+lo), extract index, diff partial,
// scatter embed_sum [e][d] (coalesced) + count. 1 wave per row. (R5 verbatim)
__global__ __launch_bounds__(256) void gather_update_kernel(
    const float* __restrict__ z, const unsigned short* __restrict__ e_hi,
    const unsigned short* __restrict__ e_lo,
    const unsigned long long* __restrict__ pack, float* __restrict__ out_q,
    float* __restrict__ out_idx, float* __restrict__ embsum,
    float* __restrict__ count, float* __restrict__ diff_acc) {
  const int row = blockIdx.x * 4 + (threadIdx.x >> 6);
  const int lane = threadIdx.x & 63;
  const int e = (int)(pack[row] & 8191ULL);
  if (lane == 0) out_idx[row] = (float)e;
  const float4 zv =
      *reinterpret_cast<const float4*>(&z[(size_t)row * DIMC + lane * 4]);
  const ushort4 h =
      *reinterpret_cast<const ushort4*>(&e_hi[(size_t)e * DIMC + lane * 4]);
  const ushort4 l =
      *reinterpret_cast<const ushort4*>(&e_lo[(size_t)e * DIMC + lane * 4]);
  const float q0 = bf16_f(h.x) + bf16_f(l.x);
  const float q1 = bf16_f(h.y) + bf16_f(l.y);
  const float q2 = bf16_f(h.z) + bf16_f(l.z);
  const float q3 = bf16_f(h.w) + bf16_f(l.w);
  const float d0 = q0 - zv.x, d1 = q1 - zv.y, d2 = q2 - zv.z, d3 = q3 - zv.w;
  float4 st;
  st.x = zv.x + d0; st.y = zv.y + d1; st.z = zv.z + d2; st.w = zv.w + d3;
  *reinterpret_cast<float4*>(&out_q[(size_t)row * DIMC + lane * 4]) = st;

  atomicAdd(&embsum[(size_t)e * DIMC + lane * 4 + 0], zv.x);
  atomicAdd(&embsum[(size_t)e * DIMC + lane * 4 + 1], zv.y);
  atomicAdd(&embsum[(size_t)e * DIMC + lane * 4 + 2], zv.z);
  atomicAdd(&embsum[(size_t)e * DIMC + lane * 4 + 3], zv.w);

  float local = d0 * d0 + d1 * d1 + d2 * d2 + d3 * d3;
#pragma unroll
  for (int off = 32; off > 0; off >>= 1) local += __shfl_down(local, off, 64);

  __shared__ float dred[4];
  if (lane == 0) {
    dred[threadIdx.x >> 6] = local;
    atomicAdd(&count[e], 1.0f);
  }
  __syncthreads();
  if (threadIdx.x == 0)
    atomicAdd(diff_acc, dred[0] + dred[1] + dred[2] + dred[3]);
}

// ---------------------------------------------------------------------------
// fin1 (R5 verbatim): blocks [0,512): new_embedding[d][e] = (0.99*eavg +
// 0.01*embsum[e][d]) * (1/smoothed(e)) — transpose + EMA + divide, one pass.
// blocks [512,544): new_cluster_size + diff finalize.
__global__ __launch_bounds__(256) void fin1_kernel(
    const float* __restrict__ eavg, const float* __restrict__ embsum,
    const float* __restrict__ cs, const float* __restrict__ count,
    const float* __restrict__ n_ptr, const float* __restrict__ diff_acc,
    float* __restrict__ out_emb, float* __restrict__ out_ncs,
    float* __restrict__ out_diff) {
  const int b = blockIdx.x;
  const int t = threadIdx.x;
  __shared__ float tile[64][68];
  __shared__ float rs[64];
  if (b < 512) {
    const int e0 = (b & 127) * 64;
    const int d0 = (b >> 7) * 64;
    const int c4 = (t & 15) * 4;
    const int rr = t >> 4;
    if (t < 64) {
      const float n = n_ptr[0];
      const float ncs = cs[e0 + t] * 0.99f + 0.01f * count[e0 + t];
      const float sm = (ncs + 1e-5f) / (n + 0.08192f) * n;
      rs[t] = 1.0f / sm;
    }
#pragma unroll
    for (int i = 0; i < 4; ++i) {
      const int er = rr + i * 16;
      const float4 v = *reinterpret_cast<const float4*>(
          &embsum[(size_t)(e0 + er) * DIMC + d0 + c4]);
      *reinterpret_cast<float4*>(&tile[er][c4]) = v;
    }
    __syncthreads();
#pragma unroll
    for (int i = 0; i < 4; ++i) {
      const int dr = rr + i * 16;
      const size_t g = (size_t)(d0 + dr) * NEMB + e0 + c4;
      const float4 av = *reinterpret_cast<const float4*>(&eavg[g]);
      float4 o;
      o.x = (av.x * 0.99f + 0.01f * tile[c4 + 0][dr]) * rs[c4 + 0];
      o.y = (av.y * 0.99f + 0.01f * tile[c4 + 1][dr]) * rs[c4 + 1];
      o.z = (av.z * 0.99f + 0.01f * tile[c4 + 2][dr]) * rs[c4 + 2];
      o.w = (av.w * 0.99f + 0.01f * tile[c4 + 3][dr]) * rs[c4 + 3];
      *reinterpret_cast<float4*>(&out_emb[g]) = o;
    }
  } else {
    const int g = (b - 512) * 256 + t;
    out_ncs[g] = cs[g] * 0.99f + 0.01f * count[g];
    if (g == 0) out_diff[0] = diff_acc[0] * (1.0f / 4194304.0f);
  }
}

// ---------------------------------------------------------------------------
// fin2b (R5 verbatim): new_embedding_avg[g] = new_embedding[g] * smoothed(e).
__global__ __launch_bounds__(256) void fin2b_kernel(
    const float* __restrict__ cs, const float* __restrict__ count,
    const float* __restrict__ n_ptr, const float* __restrict__ out_emb,
    float* __restrict__ out_avg) {
  const int g = blockIdx.x * 256 + threadIdx.x;
  const int e = g & 8191;
  const float n = n_ptr[0];
  const float ncs = cs[e] * 0.99f + 0.01f * count[e];
  const float sm = (ncs + 1e-5f) / (n + 0.08192f) * n;
  out_avg[g] = out_emb[g] * sm;
}

// ---------------------------------------------------------------------------
extern "C" void kernel_launch(void* const* d_in, const int* in_sizes, int n_in,
                              void* d_out, int out_size, void* d_ws,
                              size_t ws_size, hipStream_t stream) {
  const float* z = (const float*)d_in[0];
  const float* emb = (const float*)d_in[1];
  const float* cs = (const float*)d_in[2];
  const float* eavg = (const float*)d_in[3];
  float* out = (float*)d_out;
  float* ws = (float*)d_ws;

  unsigned short* e_hi = (unsigned short*)(ws + WS_EHI);
  unsigned short* e_lo = (unsigned short*)(ws + WS_ELO);
  float* ws_count = ws + WS_COUNT;
  float* ws_diff = ws + WS_DIFF;
  float* ws_n = ws + WS_N;
  float* ws_enorm = ws + WS_ENORM;
  unsigned long long* ws_pack = (unsigned long long*)(ws + WS_PACK);

  // d_out-aliased scratch (rewritten before readback):
  unsigned short* z_hi = (unsigned short*)(out + OUT_Q);
  unsigned short* z_lo = (unsigned short*)(out + OUT_Q + 2097152);
  float* embsum = out + OUT_NEWAVG;  // [e][d]

  prep_kernel<<<2186, 256, 0, stream>>>(z, emb, cs, z_hi, z_lo, e_hi, e_lo,
                                        ws_enorm, embsum, ws_pack, ws_count,
                                        ws_n);
  argmin_mfma_kernel<<<512, 512, 0, stream>>>(z_hi, z_lo, e_hi, e_lo, ws_enorm,
                                              ws_pack);
  gather_update_kernel<<<NROWS / 4, 256, 0, stream>>>(
      z, e_hi, e_lo, ws_pack, out + OUT_Q, out + OUT_IDX, embsum, ws_count,
      ws_diff);
  fin1_kernel<<<544, 256, 0, stream>>>(eavg, embsum, cs, ws_count, ws_n,
                                       ws_diff, out + OUT_NEWEMB,
                                       out + OUT_NEWCS, out + OUT_DIFF);
  fin2b_kernel<<<(DIMC * NEMB) / 256, 256, 0, stream>>>(
      cs, ws_count, ws_n, out + OUT_NEWEMB, out + OUT_NEWAVG);
}